// Round 6
// baseline (398.351 us; speedup 1.0000x reference)
//
#include <hip/hip_runtime.h>
#include <hip/hip_fp16.h>
#include <math.h>

#define N_NODES 50000
#define N_EDGES 800000
#define FEAT 128
#define EPS_W 1e-12f

// bucket = node >> 8 : 256 nodes per bucket, 196 buckets covers 50000
#define NB_BUCKET 196
#define NBLK_AB 128          // blocks for hist/scatter passes
#define CHUNK 6250           // edges per pass block (128*6250 = 800000)
#define SCAN_N (NB_BUCKET * NBLK_AB)   // 25088
#define GEMM_BLOCKS 3125     // 50000 / 16

typedef unsigned long long u64;
typedef _Float16 f16x8 __attribute__((ext_vector_type(8)));
typedef float f32x4 __attribute__((ext_vector_type(4)));

// ---------- helpers ----------
__device__ __forceinline__ float selu_f(float x) {
  const float scale = 1.0507009873554805f;
  const float alpha = 1.6732632423543772f;
  return x > 0.f ? scale * x : scale * alpha * expm1f(x);
}

__device__ __forceinline__ float2 h2f2(unsigned int u) {
  __half2 h = *reinterpret_cast<__half2*>(&u);
  return __half22float2(h);
}

// ---------- GEMM body: 16 rows of A (n x 128) @ W (128 x 128) -> fp16 out ------
__device__ __forceinline__ void gemm16_half_body(
    const float* __restrict__ A, const float* __restrict__ W,
    __half* __restrict__ out, int row0, int n, float* aL /*16*128 LDS*/) {
  for (int i = threadIdx.x; i < 16 * 128; i += 256) {
    int r = row0 + (i >> 7);
    aL[i] = (r < n) ? A[row0 * 128 + i] : 0.f;
  }
  __syncthreads();
  int col = threadIdx.x & 63;
  int rg = threadIdx.x >> 6;  // 0..3
  float acc[4][2] = {};
  const float4* a4 = (const float4*)&aL[rg * 4 * 128];
#pragma unroll 8
  for (int k4 = 0; k4 < 32; ++k4) {
    float w0 = W[(4 * k4 + 0) * 128 + col];
    float w1 = W[(4 * k4 + 1) * 128 + col];
    float w2 = W[(4 * k4 + 2) * 128 + col];
    float w3 = W[(4 * k4 + 3) * 128 + col];
    float e0 = W[(4 * k4 + 0) * 128 + col + 64];
    float e1 = W[(4 * k4 + 1) * 128 + col + 64];
    float e2 = W[(4 * k4 + 2) * 128 + col + 64];
    float e3 = W[(4 * k4 + 3) * 128 + col + 64];
#pragma unroll
    for (int r = 0; r < 4; ++r) {
      float4 a = a4[r * 32 + k4];
      acc[r][0] += a.x * w0 + a.y * w1 + a.z * w2 + a.w * w3;
      acc[r][1] += a.x * e0 + a.y * e1 + a.z * e2 + a.w * e3;
    }
  }
#pragma unroll
  for (int r = 0; r < 4; ++r) {
    int row = row0 + rg * 4 + r;
    if (row < n) {
      out[(size_t)row * 128 + col]      = __float2half_rn(acc[r][0]);
      out[(size_t)row * 128 + col + 64] = __float2half_rn(acc[r][1]);
    }
  }
}

// ---------- 1. per-block bucket histograms + W2 fragment transform ----------
// Block NBLK_AB: transform W2 (fp32 [k][col]) into fragment-major fp16 for
// mfma_f32_16x16x32_f16: w2h[((nt*4+ks)*64+l)*8 + j] = W2[ks*32+(l>>4)*8+j][nt*16+(l&15)]
__global__ __launch_bounds__(256) void pass_hist(
    const int* __restrict__ src, const int* __restrict__ dst,
    int* __restrict__ dMat, int* __restrict__ sMat,
    const float* __restrict__ W2, __half* __restrict__ w2h) {
  if (blockIdx.x == NBLK_AB) {
    for (int f = threadIdx.x; f < 2048; f += 256) {
      int l = f & 63, ks = (f >> 6) & 3, nt = f >> 8;
      int kbase = ks * 32 + (l >> 4) * 8;
      int col = nt * 16 + (l & 15);
      __align__(16) __half tmp[8];
#pragma unroll
      for (int j = 0; j < 8; ++j)
        tmp[j] = __float2half_rn(W2[(kbase + j) * 128 + col]);
      *(uint4*)&w2h[f * 8] = *(const uint4*)tmp;
    }
    return;
  }
  __shared__ int hd[NB_BUCKET], hs[NB_BUCKET];
  for (int i = threadIdx.x; i < NB_BUCKET; i += 256) { hd[i] = 0; hs[i] = 0; }
  __syncthreads();
  int blk = blockIdx.x;
  int base = blk * CHUNK;
  for (int i = threadIdx.x; i < CHUNK; i += 256) {
    int e = base + i;
    atomicAdd(&hd[dst[e] >> 8], 1);
    atomicAdd(&hs[src[e] >> 8], 1);
  }
  __syncthreads();
  for (int i = threadIdx.x; i < NB_BUCKET; i += 256) {
    dMat[i * NBLK_AB + blk] = hd[i];
    sMat[i * NBLK_AB + blk] = hs[i];
  }
}

// ---------- 2. in-place exclusive scan of the two 25088-entry matrices --------
__global__ __launch_bounds__(1024) void scan_mat(int* __restrict__ dMat,
                                                 int* __restrict__ sMat) {
  int* m = (blockIdx.x == 0) ? dMat : sMat;
  __shared__ int sh[1024];
  int t = threadIdx.x;
  const int CH = 25;  // 1024*25 = 25600 >= 25088
  int s0 = t * CH;
  int v[CH];
  int sum = 0;
#pragma unroll
  for (int j = 0; j < CH; ++j) {
    int idx = s0 + j;
    v[j] = (idx < SCAN_N) ? m[idx] : 0;
    sum += v[j];
  }
  sh[t] = sum;
  __syncthreads();
  for (int off = 1; off < 1024; off <<= 1) {
    int x = (t >= off) ? sh[t - off] : 0;
    __syncthreads();
    sh[t] += x;
    __syncthreads();
  }
  int excl = sh[t] - sum;
#pragma unroll
  for (int j = 0; j < CH; ++j) {
    int idx = s0 + j;
    if (idx < SCAN_N) { m[idx] = excl; excl += v[j]; }
  }
}

// ---------- 3. FUSED: exact-slot bucket scatter (no global atomics) || GEMM ---
// dRec: int2 { (src<<8)|dstLow, ew_bits }   sRec: u32 { srcLow<<24 | Q23(ew) }
__global__ __launch_bounds__(256) void fused_scatter_gemm(
    const int* __restrict__ src, const int* __restrict__ dst,
    const float* __restrict__ ew,
    const int* __restrict__ dMat, const int* __restrict__ sMat,
    int2* __restrict__ dRec, unsigned* __restrict__ sRec,
    const float* __restrict__ x, const float* __restrict__ W1,
    __half* __restrict__ bufG) {
  __shared__ float aL[16 * 128];
  __shared__ int curD[NB_BUCKET], curS[NB_BUCKET];
  if (blockIdx.x >= NBLK_AB) {
    gemm16_half_body(x, W1, bufG, (blockIdx.x - NBLK_AB) * 16, N_NODES, aL);
    return;
  }
  int blk = blockIdx.x;
  for (int i = threadIdx.x; i < NB_BUCKET; i += 256) {
    curD[i] = dMat[i * NBLK_AB + blk];
    curS[i] = sMat[i * NBLK_AB + blk];
  }
  __syncthreads();
  int base = blk * CHUNK;
  for (int i = threadIdx.x; i < CHUNK; i += 256) {
    int e = base + i;
    int s = src[e], d = dst[e];
    float w = ew[e];
    int pd = atomicAdd(&curD[d >> 8], 1);           // LDS atomic
    int2 r; r.x = (s << 8) | (d & 255); r.y = __float_as_int(w);
    dRec[pd] = r;
    int ps = atomicAdd(&curS[s >> 8], 1);           // LDS atomic
    unsigned q = (unsigned)__float2uint_rn(w * 8388608.0f) & 0xFFFFFFu;  // Q23
    sRec[ps] = ((unsigned)(s & 255) << 24) | q;
  }
}

// ---------- 4. per-bucket src reduction -> inv_out ----------
__global__ __launch_bounds__(256) void bucket_src_reduce(
    const unsigned* __restrict__ sRec, const int* __restrict__ sMat,
    float* __restrict__ inv_out) {
  __shared__ float wdeg[256];
  __shared__ int cnt[256];
  int b = blockIdx.x, t = threadIdx.x;
  wdeg[t] = 0.f; cnt[t] = 0;
  __syncthreads();
  int s0 = sMat[b * NBLK_AB];
  int s1 = (b == NB_BUCKET - 1) ? N_EDGES : sMat[(b + 1) * NBLK_AB];
  for (int i = s0 + t; i < s1; i += 256) {
    unsigned r = sRec[i];
    int node = r >> 24;
    float w = (float)(r & 0xFFFFFFu) * (1.0f / 8388608.0f);
    atomicAdd(&wdeg[node], w);
    atomicAdd(&cnt[node], 1);
  }
  __syncthreads();
  int nodeg = b * 256 + t;
  if (nodeg < N_NODES) {
    inv_out[nodeg] = (1.0f / sqrtf(fmaxf(wdeg[t], EPS_W))) *
                     (1.0f / sqrtf(fmaxf((float)cnt[t], 1.0f)));
  }
}

// ---------- 5. per-bucket dst build: rowptr + rank + final CSR edges ----------
__global__ __launch_bounds__(256) void bucket_dst_build(
    const int2* __restrict__ dRec, const int* __restrict__ dMat,
    const float* __restrict__ inv_out,
    int* __restrict__ rowptr, int2* __restrict__ edges) {
  __shared__ float wdeg[256];
  __shared__ int cnt[256];
  __shared__ int excl[256];
  __shared__ float invin[256];
  __shared__ int cur[256];
  int b = blockIdx.x, t = threadIdx.x;
  wdeg[t] = 0.f; cnt[t] = 0;
  __syncthreads();
  int s0 = dMat[b * NBLK_AB];
  int s1 = (b == NB_BUCKET - 1) ? N_EDGES : dMat[(b + 1) * NBLK_AB];
  for (int i = s0 + t; i < s1; i += 256) {
    int2 r = dRec[i];
    int node = r.x & 255;
    atomicAdd(&cnt[node], 1);
    atomicAdd(&wdeg[node], __int_as_float(r.y));
  }
  __syncthreads();
  int myc = cnt[t];
  excl[t] = myc;
  __syncthreads();
  for (int off = 1; off < 256; off <<= 1) {
    int x = (t >= off) ? excl[t - off] : 0;
    __syncthreads();
    excl[t] += x;
    __syncthreads();
  }
  int myexcl = excl[t] - myc;
  int nodeg = b * 256 + t;
  if (nodeg < N_NODES) rowptr[nodeg] = s0 + myexcl;
  if (b == NB_BUCKET - 1 && t == 0) rowptr[N_NODES] = N_EDGES;
  invin[t] = (1.0f / sqrtf(fmaxf(wdeg[t], EPS_W))) *
             (1.0f / sqrtf(fmaxf((float)cnt[t], 1.0f)));
  cur[t] = s0 + myexcl;
  __syncthreads();
  for (int i = s0 + t; i < s1; i += 256) {
    int2 r = dRec[i];
    int node = r.x & 255;
    int srcn = ((unsigned)r.x) >> 8;
    float w = __int_as_float(r.y);
    float c = w * inv_out[srcn] * invin[node];
    int pos = atomicAdd(&cur[node], 1);             // LDS atomic -> rank
    int2 rec; rec.x = srcn; rec.y = __float_as_int(c);
    edges[pos] = rec;
  }
}

// ---------- half-wave gather: 32 lanes cover a 128-wide fp16 row ----------
__device__ __forceinline__ float4 gather_row_half(
    const int* __restrict__ rowptr, const int2* __restrict__ edges,
    const uint2* __restrict__ xh /* row stride 32 */, int row, int sub) {
  int beg = rowptr[row], end = rowptr[row + 1];
  float4 acc = make_float4(0.f, 0.f, 0.f, 0.f);
  int e = beg;
  for (; e + 7 < end; e += 8) {
    int2 p0 = edges[e + 0], p1 = edges[e + 1], p2 = edges[e + 2], p3 = edges[e + 3];
    int2 p4 = edges[e + 4], p5 = edges[e + 5], p6 = edges[e + 6], p7 = edges[e + 7];
    uint2 q0 = xh[(size_t)p0.x * 32 + sub];
    uint2 q1 = xh[(size_t)p1.x * 32 + sub];
    uint2 q2 = xh[(size_t)p2.x * 32 + sub];
    uint2 q3 = xh[(size_t)p3.x * 32 + sub];
    uint2 q4 = xh[(size_t)p4.x * 32 + sub];
    uint2 q5 = xh[(size_t)p5.x * 32 + sub];
    uint2 q6 = xh[(size_t)p6.x * 32 + sub];
    uint2 q7 = xh[(size_t)p7.x * 32 + sub];
#define ACC_EDGE(P, Q)                                              \
    {                                                               \
      float cc = __int_as_float(P.y);                               \
      float2 lo = h2f2(Q.x);                                        \
      float2 hi = h2f2(Q.y);                                        \
      acc.x += cc * lo.x; acc.y += cc * lo.y;                       \
      acc.z += cc * hi.x; acc.w += cc * hi.y;                       \
    }
    ACC_EDGE(p0, q0) ACC_EDGE(p1, q1) ACC_EDGE(p2, q2) ACC_EDGE(p3, q3)
    ACC_EDGE(p4, q4) ACC_EDGE(p5, q5) ACC_EDGE(p6, q6) ACC_EDGE(p7, q7)
  }
  for (; e < end; ++e) {
    int2 p0 = edges[e];
    uint2 q0 = xh[(size_t)p0.x * 32 + sub];
    ACC_EDGE(p0, q0)
  }
#undef ACC_EDGE
  return acc;
}

// ---------- 6a. layer-1: spmm + bias + selu + MFMA @W2 -> fp16 bufB ----------
// 16 rows/block: gather in 2 reps of 8 half-wave rows; h stored fp16 in LDS
// (pad to 136 halfs/row -> 2-way bank aliasing, free). GEMM = 8 MFMA/wave.
__global__ __launch_bounds__(256) void spmm_selu_gemm(
    const int* __restrict__ rowptr, const int2* __restrict__ edges,
    const uint2* __restrict__ g, const float* __restrict__ bias,
    const __half* __restrict__ w2h, __half* __restrict__ out) {
  __shared__ __half hL[16 * 136];
  int wid = threadIdx.x >> 6, lane = threadIdx.x & 63;
  int half_ = lane >> 5, sub = lane & 31;
#pragma unroll
  for (int rep = 0; rep < 2; ++rep) {
    int lrow = rep * 8 + wid * 2 + half_;
    int row = blockIdx.x * 16 + lrow;                // grid exact: row < n
    float4 a = gather_row_half(rowptr, edges, g, row, sub);
    float4 b = ((const float4*)bias)[sub];
    __half2* hp = (__half2*)&hL[lrow * 136 + sub * 4];
    hp[0] = __floats2half2_rn(selu_f(a.x + b.x), selu_f(a.y + b.y));
    hp[1] = __floats2half2_rn(selu_f(a.z + b.z), selu_f(a.w + b.w));
  }
  __syncthreads();
  // C[16x128] = hL @ W2 ; wave w owns col-tiles 2w, 2w+1
  f32x4 acc0 = {0.f, 0.f, 0.f, 0.f}, acc1 = {0.f, 0.f, 0.f, 0.f};
  const f16x8* w8 = (const f16x8*)w2h;
#pragma unroll
  for (int ks = 0; ks < 4; ++ks) {
    f16x8 af = *(const f16x8*)&hL[(lane & 15) * 136 + ks * 32 + (lane >> 4) * 8];
    f16x8 bf0 = w8[((wid * 2 + 0) * 4 + ks) * 64 + lane];
    f16x8 bf1 = w8[((wid * 2 + 1) * 4 + ks) * 64 + lane];
    acc0 = __builtin_amdgcn_mfma_f32_16x16x32_f16(af, bf0, acc0, 0, 0, 0);
    acc1 = __builtin_amdgcn_mfma_f32_16x16x32_f16(af, bf1, acc1, 0, 0, 0);
  }
  // C/D layout: col = lane&15 (+16*tile), row = (lane>>4)*4 + reg
  int crow = blockIdx.x * 16 + (lane >> 4) * 4;
  int c0 = wid * 32 + (lane & 15);
#pragma unroll
  for (int r = 0; r < 4; ++r) {
    out[(size_t)(crow + r) * 128 + c0]      = __float2half_rn(acc0[r]);
    out[(size_t)(crow + r) * 128 + c0 + 16] = __float2half_rn(acc1[r]);
  }
}

// ---------- 6b. layer-2: XCD-column-sharded spmm + bias + selu -> fp32 --------
// col-group = blockIdx&7 -> each XCD touches only a 1.6 MB slice of bufB
// (L2-resident). 2 lanes x 16B cover the 32B slice of a row; 128 rows/block.
#define EP_RPB 128
#define EP_RT ((N_NODES + EP_RPB - 1) / EP_RPB)   // 391
#define ACC8(P, Q)                                                        \
  {                                                                       \
    float cc = __int_as_float((int)((P) >> 32));                          \
    float2 f0 = h2f2((Q).x), f1 = h2f2((Q).y);                            \
    float2 f2 = h2f2((Q).z), f3 = h2f2((Q).w);                            \
    acc[0] += cc * f0.x; acc[1] += cc * f0.y;                             \
    acc[2] += cc * f1.x; acc[3] += cc * f1.y;                             \
    acc[4] += cc * f2.x; acc[5] += cc * f2.y;                             \
    acc[6] += cc * f3.x; acc[7] += cc * f3.y;                             \
  }
__global__ __launch_bounds__(256) void spmm_ep(
    const int* __restrict__ rowptr, const int2* __restrict__ edges,
    const uint4* __restrict__ xq /* bufB as uint4, ROW STRIDE 16 */,
    const float* __restrict__ bias, float* __restrict__ out) {
  int cg = blockIdx.x & 7;                       // col-group -> XCD affinity
  int row = (blockIdx.x >> 3) * EP_RPB + (threadIdx.x >> 1);
  int lp = threadIdx.x & 1;
  if (row >= N_NODES) return;
  int beg = rowptr[row], end = rowptr[row + 1];
  const uint4* xb = xq + cg * 2 + lp;
  float acc[8] = {0.f, 0.f, 0.f, 0.f, 0.f, 0.f, 0.f, 0.f};
  int e = beg;
  for (; e + 3 < end; e += 4) {
    u64 p0 = __builtin_nontemporal_load((const u64*)(edges + e + 0));
    u64 p1 = __builtin_nontemporal_load((const u64*)(edges + e + 1));
    u64 p2 = __builtin_nontemporal_load((const u64*)(edges + e + 2));
    u64 p3 = __builtin_nontemporal_load((const u64*)(edges + e + 3));
    uint4 q0 = xb[(size_t)(unsigned)(p0 & 0xffffffffu) * 16];
    uint4 q1 = xb[(size_t)(unsigned)(p1 & 0xffffffffu) * 16];
    uint4 q2 = xb[(size_t)(unsigned)(p2 & 0xffffffffu) * 16];
    uint4 q3 = xb[(size_t)(unsigned)(p3 & 0xffffffffu) * 16];
    ACC8(p0, q0) ACC8(p1, q1) ACC8(p2, q2) ACC8(p3, q3)
  }
  for (; e < end; ++e) {
    u64 p0 = __builtin_nontemporal_load((const u64*)(edges + e));
    uint4 q0 = xb[(size_t)(unsigned)(p0 & 0xffffffffu) * 16];
    ACC8(p0, q0)
  }
  const float* bb = bias + cg * 16 + lp * 8;
  f32x4 o0, o1;
  o0[0] = selu_f(acc[0] + bb[0]); o0[1] = selu_f(acc[1] + bb[1]);
  o0[2] = selu_f(acc[2] + bb[2]); o0[3] = selu_f(acc[3] + bb[3]);
  o1[0] = selu_f(acc[4] + bb[4]); o1[1] = selu_f(acc[5] + bb[5]);
  o1[2] = selu_f(acc[6] + bb[6]); o1[3] = selu_f(acc[7] + bb[7]);
  f32x4* op = (f32x4*)(out + (size_t)row * 128 + cg * 16 + lp * 8);
  __builtin_nontemporal_store(o0, op);
  __builtin_nontemporal_store(o1, op + 1);
}

extern "C" void kernel_launch(void* const* d_in, const int* in_sizes, int n_in,
                              void* d_out, int out_size, void* d_ws, size_t ws_size,
                              hipStream_t stream) {
  const float* x   = (const float*)d_in[0];
  const int*   src = (const int*)d_in[1];
  const int*   dst = (const int*)d_in[2];
  const float* ew  = (const float*)d_in[3];
  const float* W1  = (const float*)d_in[4];
  const float* b1  = (const float*)d_in[5];
  const float* W2  = (const float*)d_in[6];
  const float* b2  = (const float*)d_in[7];
  float* out = (float*)d_out;

  // workspace layout (temporal aliasing: edges over sRec; dRec over bufB)
  char* ws = (char*)d_ws;
  int*   dMat    = (int*)(ws + 0);              //   100,352 B
  int*   sMat    = (int*)(ws + 100352);         //   100,352 B -> 200,704
  float* inv_out = (float*)(ws + 200704);       //   200,000 B -> 400,704
  int*   rowptr  = (int*)(ws + 400704);         //   200,004 B -> 600,708
  __half* w2h    = (__half*)(ws + 600720);      //    32,768 B -> 633,488 (16B)
  // union region A: sRec (3.2 MB, dead after bucket_src_reduce) / edges (6.4 MB)
  unsigned* sRec = (unsigned*)(ws + 633488);
  int2*  edges   = (int2*)(ws + 633488);        // -> 7,033,488
  __half* bufG   = (__half*)(ws + 7033488);     // 12.8 MB -> 19,833,488
  // union region B: dRec (6.4 MB, dead before spmm_selu_gemm writes bufB)
  int2*  dRec    = (int2*)(ws + 19833488);
  __half* bufB   = (__half*)(ws + 19833488);    // 12.8 MB -> 32,633,488

  // 1. bucket histograms (src & dst) + W2 fragment transform
  pass_hist<<<NBLK_AB + 1, 256, 0, stream>>>(src, dst, dMat, sMat, W2, w2h);
  // 2. exclusive scan of both count matrices
  scan_mat<<<2, 1024, 0, stream>>>(dMat, sMat);
  // 3. exact-slot scatter into bucket regions || bufG = fp16(x @ W1)
  fused_scatter_gemm<<<NBLK_AB + GEMM_BLOCKS, 256, 0, stream>>>(
      src, dst, ew, dMat, sMat, dRec, sRec, x, W1, bufG);
  // 4. src-side reduction -> inv_out
  bucket_src_reduce<<<NB_BUCKET, 256, 0, stream>>>(sRec, sMat, inv_out);
  // 5. dst-side build -> rowptr + final CSR edges (src, c)
  bucket_dst_build<<<NB_BUCKET, 256, 0, stream>>>(dRec, dMat, inv_out,
                                                  rowptr, edges);

  // layer 1 + layer-2 GEMM: bufB = fp16( selu(A_hat·(x@W1) + b1) ) @ W2 (MFMA)
  spmm_selu_gemm<<<GEMM_BLOCKS, 256, 0, stream>>>(
      rowptr, edges, (const uint2*)bufG, b1, w2h, bufB);
  // layer 2: out = selu(A_hat·bufB + b2), XCD-column-sharded
  spmm_ep<<<EP_RT * 8, 256, 0, stream>>>(rowptr, edges, (const uint4*)bufB,
                                         b2, out);
}

// Round 7
// 267.066 us; speedup vs baseline: 1.4916x; 1.4916x over previous
//
#include <hip/hip_runtime.h>
#include <hip/hip_fp16.h>
#include <math.h>

#define N_NODES 50000
#define N_EDGES 800000
#define FEAT 128
#define EPS_W 1e-12f

// bucket = node >> 8 : 256 nodes per bucket, 196 buckets covers 50000
#define NB_BUCKET 196
#define NBLK_AB 256          // blocks for hist/scatter passes
#define CHUNK 3125           // edges per pass block (256*3125 = 800000)
#define SCAN_N (NB_BUCKET * NBLK_AB)   // 50176 = 49*1024 exactly
#define GEMM_BLOCKS 3125     // 50000 / 16

typedef unsigned long long u64;
typedef _Float16 f16x8 __attribute__((ext_vector_type(8)));
typedef float f32x4 __attribute__((ext_vector_type(4)));

// ---------- helpers ----------
__device__ __forceinline__ float selu_f(float x) {
  const float scale = 1.0507009873554805f;
  const float alpha = 1.6732632423543772f;
  return x > 0.f ? scale * x : scale * alpha * expm1f(x);
}

__device__ __forceinline__ float2 h2f2(unsigned int u) {
  __half2 h = *reinterpret_cast<__half2*>(&u);
  return __half22float2(h);
}

// ---------- GEMM body: 16 rows of A (n x 128) @ W (128 x 128) -> fp16 out ------
__device__ __forceinline__ void gemm16_half_body(
    const float* __restrict__ A, const float* __restrict__ W,
    __half* __restrict__ out, int row0, int n, float* aL /*16*128 LDS*/) {
  for (int i = threadIdx.x; i < 16 * 128; i += 256) {
    int r = row0 + (i >> 7);
    aL[i] = (r < n) ? A[row0 * 128 + i] : 0.f;
  }
  __syncthreads();
  int col = threadIdx.x & 63;
  int rg = threadIdx.x >> 6;  // 0..3
  float acc[4][2] = {};
  const float4* a4 = (const float4*)&aL[rg * 4 * 128];
#pragma unroll 8
  for (int k4 = 0; k4 < 32; ++k4) {
    float w0 = W[(4 * k4 + 0) * 128 + col];
    float w1 = W[(4 * k4 + 1) * 128 + col];
    float w2 = W[(4 * k4 + 2) * 128 + col];
    float w3 = W[(4 * k4 + 3) * 128 + col];
    float e0 = W[(4 * k4 + 0) * 128 + col + 64];
    float e1 = W[(4 * k4 + 1) * 128 + col + 64];
    float e2 = W[(4 * k4 + 2) * 128 + col + 64];
    float e3 = W[(4 * k4 + 3) * 128 + col + 64];
#pragma unroll
    for (int r = 0; r < 4; ++r) {
      float4 a = a4[r * 32 + k4];
      acc[r][0] += a.x * w0 + a.y * w1 + a.z * w2 + a.w * w3;
      acc[r][1] += a.x * e0 + a.y * e1 + a.z * e2 + a.w * e3;
    }
  }
#pragma unroll
  for (int r = 0; r < 4; ++r) {
    int row = row0 + rg * 4 + r;
    if (row < n) {
      out[(size_t)row * 128 + col]      = __float2half_rn(acc[r][0]);
      out[(size_t)row * 128 + col + 64] = __float2half_rn(acc[r][1]);
    }
  }
}

// ---------- 1. per-block bucket histograms + W2 fragment transform ----------
// Block NBLK_AB: transform W2 (fp32 [k][col]) into fragment-major fp16 for
// mfma_f32_16x16x32_f16: w2h[((nt*4+ks)*64+l)*8 + j] = W2[ks*32+(l>>4)*8+j][nt*16+(l&15)]
__global__ __launch_bounds__(256) void pass_hist(
    const int* __restrict__ src, const int* __restrict__ dst,
    int* __restrict__ dMat, int* __restrict__ sMat,
    const float* __restrict__ W2, __half* __restrict__ w2h) {
  if (blockIdx.x == NBLK_AB) {
    for (int f = threadIdx.x; f < 2048; f += 256) {
      int l = f & 63, ks = (f >> 6) & 3, nt = f >> 8;
      int kbase = ks * 32 + (l >> 4) * 8;
      int col = nt * 16 + (l & 15);
      __align__(16) __half tmp[8];
#pragma unroll
      for (int j = 0; j < 8; ++j)
        tmp[j] = __float2half_rn(W2[(kbase + j) * 128 + col]);
      *(uint4*)&w2h[f * 8] = *(const uint4*)tmp;
    }
    return;
  }
  __shared__ int hd[NB_BUCKET], hs[NB_BUCKET];
  for (int i = threadIdx.x; i < NB_BUCKET; i += 256) { hd[i] = 0; hs[i] = 0; }
  __syncthreads();
  int blk = blockIdx.x;
  int base = blk * CHUNK;
  for (int i = threadIdx.x; i < CHUNK; i += 256) {
    int e = base + i;
    atomicAdd(&hd[dst[e] >> 8], 1);
    atomicAdd(&hs[src[e] >> 8], 1);
  }
  __syncthreads();
  for (int i = threadIdx.x; i < NB_BUCKET; i += 256) {
    dMat[i * NBLK_AB + blk] = hd[i];
    sMat[i * NBLK_AB + blk] = hs[i];
  }
}

// ---------- 2. in-place exclusive scan of the two 50176-entry matrices --------
__global__ __launch_bounds__(1024) void scan_mat(int* __restrict__ dMat,
                                                 int* __restrict__ sMat) {
  int* m = (blockIdx.x == 0) ? dMat : sMat;
  __shared__ int sh[1024];
  int t = threadIdx.x;
  const int CH = 49;  // 1024*49 = 50176 == SCAN_N exactly
  int s0 = t * CH;
  int v[CH];
  int sum = 0;
#pragma unroll
  for (int j = 0; j < CH; ++j) {
    v[j] = m[s0 + j];
    sum += v[j];
  }
  sh[t] = sum;
  __syncthreads();
  for (int off = 1; off < 1024; off <<= 1) {
    int x = (t >= off) ? sh[t - off] : 0;
    __syncthreads();
    sh[t] += x;
    __syncthreads();
  }
  int excl = sh[t] - sum;
#pragma unroll
  for (int j = 0; j < CH; ++j) {
    m[s0 + j] = excl;
    excl += v[j];
  }
}

// ---------- 3. FUSED: exact-slot bucket scatter (no global atomics) || GEMM ---
// dRec: int2 { (src<<8)|dstLow, ew_bits }   sRec: u32 { srcLow<<24 | Q23(ew) }
__global__ __launch_bounds__(256) void fused_scatter_gemm(
    const int* __restrict__ src, const int* __restrict__ dst,
    const float* __restrict__ ew,
    const int* __restrict__ dMat, const int* __restrict__ sMat,
    int2* __restrict__ dRec, unsigned* __restrict__ sRec,
    const float* __restrict__ x, const float* __restrict__ W1,
    __half* __restrict__ bufG) {
  __shared__ float aL[16 * 128];
  __shared__ int curD[NB_BUCKET], curS[NB_BUCKET];
  if (blockIdx.x >= NBLK_AB) {
    gemm16_half_body(x, W1, bufG, (blockIdx.x - NBLK_AB) * 16, N_NODES, aL);
    return;
  }
  int blk = blockIdx.x;
  for (int i = threadIdx.x; i < NB_BUCKET; i += 256) {
    curD[i] = dMat[i * NBLK_AB + blk];
    curS[i] = sMat[i * NBLK_AB + blk];
  }
  __syncthreads();
  int base = blk * CHUNK;
  for (int i = threadIdx.x; i < CHUNK; i += 256) {
    int e = base + i;
    int s = src[e], d = dst[e];
    float w = ew[e];
    int pd = atomicAdd(&curD[d >> 8], 1);           // LDS atomic
    int2 r; r.x = (s << 8) | (d & 255); r.y = __float_as_int(w);
    dRec[pd] = r;
    int ps = atomicAdd(&curS[s >> 8], 1);           // LDS atomic
    unsigned q = (unsigned)__float2uint_rn(w * 8388608.0f) & 0xFFFFFFu;  // Q23
    sRec[ps] = ((unsigned)(s & 255) << 24) | q;
  }
}

// ---------- 4. per-bucket src reduction -> inv_out ----------
__global__ __launch_bounds__(256) void bucket_src_reduce(
    const unsigned* __restrict__ sRec, const int* __restrict__ sMat,
    float* __restrict__ inv_out) {
  __shared__ float wdeg[256];
  __shared__ int cnt[256];
  int b = blockIdx.x, t = threadIdx.x;
  wdeg[t] = 0.f; cnt[t] = 0;
  __syncthreads();
  int s0 = sMat[b * NBLK_AB];
  int s1 = (b == NB_BUCKET - 1) ? N_EDGES : sMat[(b + 1) * NBLK_AB];
  for (int i = s0 + t; i < s1; i += 256) {
    unsigned r = sRec[i];
    int node = r >> 24;
    float w = (float)(r & 0xFFFFFFu) * (1.0f / 8388608.0f);
    atomicAdd(&wdeg[node], w);
    atomicAdd(&cnt[node], 1);
  }
  __syncthreads();
  int nodeg = b * 256 + t;
  if (nodeg < N_NODES) {
    inv_out[nodeg] = (1.0f / sqrtf(fmaxf(wdeg[t], EPS_W))) *
                     (1.0f / sqrtf(fmaxf((float)cnt[t], 1.0f)));
  }
}

// ---------- 5. per-bucket dst build: rowptr + rank + final CSR edges ----------
__global__ __launch_bounds__(256) void bucket_dst_build(
    const int2* __restrict__ dRec, const int* __restrict__ dMat,
    const float* __restrict__ inv_out,
    int* __restrict__ rowptr, int2* __restrict__ edges) {
  __shared__ float wdeg[256];
  __shared__ int cnt[256];
  __shared__ int excl[256];
  __shared__ float invin[256];
  __shared__ int cur[256];
  int b = blockIdx.x, t = threadIdx.x;
  wdeg[t] = 0.f; cnt[t] = 0;
  __syncthreads();
  int s0 = dMat[b * NBLK_AB];
  int s1 = (b == NB_BUCKET - 1) ? N_EDGES : dMat[(b + 1) * NBLK_AB];
  for (int i = s0 + t; i < s1; i += 256) {
    int2 r = dRec[i];
    int node = r.x & 255;
    atomicAdd(&cnt[node], 1);
    atomicAdd(&wdeg[node], __int_as_float(r.y));
  }
  __syncthreads();
  int myc = cnt[t];
  excl[t] = myc;
  __syncthreads();
  for (int off = 1; off < 256; off <<= 1) {
    int x = (t >= off) ? excl[t - off] : 0;
    __syncthreads();
    excl[t] += x;
    __syncthreads();
  }
  int myexcl = excl[t] - myc;
  int nodeg = b * 256 + t;
  if (nodeg < N_NODES) rowptr[nodeg] = s0 + myexcl;
  if (b == NB_BUCKET - 1 && t == 0) rowptr[N_NODES] = N_EDGES;
  invin[t] = (1.0f / sqrtf(fmaxf(wdeg[t], EPS_W))) *
             (1.0f / sqrtf(fmaxf((float)cnt[t], 1.0f)));
  cur[t] = s0 + myexcl;
  __syncthreads();
  for (int i = s0 + t; i < s1; i += 256) {
    int2 r = dRec[i];
    int node = r.x & 255;
    int srcn = ((unsigned)r.x) >> 8;
    float w = __int_as_float(r.y);
    float c = w * inv_out[srcn] * invin[node];
    int pos = atomicAdd(&cur[node], 1);             // LDS atomic -> rank
    int2 rec; rec.x = srcn; rec.y = __float_as_int(c);
    edges[pos] = rec;
  }
}

// ---------- half-wave gather: 32 lanes cover a 128-wide fp16 row ----------
__device__ __forceinline__ float4 gather_row_half(
    const int* __restrict__ rowptr, const int2* __restrict__ edges,
    const uint2* __restrict__ xh /* row stride 32 */, int row, int sub) {
  int beg = rowptr[row], end = rowptr[row + 1];
  float4 acc = make_float4(0.f, 0.f, 0.f, 0.f);
  int e = beg;
  for (; e + 7 < end; e += 8) {
    int2 p0 = edges[e + 0], p1 = edges[e + 1], p2 = edges[e + 2], p3 = edges[e + 3];
    int2 p4 = edges[e + 4], p5 = edges[e + 5], p6 = edges[e + 6], p7 = edges[e + 7];
    uint2 q0 = xh[(size_t)p0.x * 32 + sub];
    uint2 q1 = xh[(size_t)p1.x * 32 + sub];
    uint2 q2 = xh[(size_t)p2.x * 32 + sub];
    uint2 q3 = xh[(size_t)p3.x * 32 + sub];
    uint2 q4 = xh[(size_t)p4.x * 32 + sub];
    uint2 q5 = xh[(size_t)p5.x * 32 + sub];
    uint2 q6 = xh[(size_t)p6.x * 32 + sub];
    uint2 q7 = xh[(size_t)p7.x * 32 + sub];
#define ACC_EDGE(P, Q)                                              \
    {                                                               \
      float cc = __int_as_float(P.y);                               \
      float2 lo = h2f2(Q.x);                                        \
      float2 hi = h2f2(Q.y);                                        \
      acc.x += cc * lo.x; acc.y += cc * lo.y;                       \
      acc.z += cc * hi.x; acc.w += cc * hi.y;                       \
    }
    ACC_EDGE(p0, q0) ACC_EDGE(p1, q1) ACC_EDGE(p2, q2) ACC_EDGE(p3, q3)
    ACC_EDGE(p4, q4) ACC_EDGE(p5, q5) ACC_EDGE(p6, q6) ACC_EDGE(p7, q7)
  }
  for (; e < end; ++e) {
    int2 p0 = edges[e];
    uint2 q0 = xh[(size_t)p0.x * 32 + sub];
    ACC_EDGE(p0, q0)
  }
#undef ACC_EDGE
  return acc;
}

// ---------- 6a. layer-1: spmm + bias + selu + MFMA @W2 -> fp16 bufB ----------
// 8 rows/block (same gather TLP as the 84.7µs r4 kernel: 6250 blocks, 2 rows
// per wave). MFMA M-dim zero-padded to 16: hL rows 8..15 are zeros; only
// C rows 0..7 are stored. GEMM = 8 MFMA/wave replacing ~256 VALU fma/thread.
__global__ __launch_bounds__(256) void spmm_selu_gemm(
    const int* __restrict__ rowptr, const int2* __restrict__ edges,
    const uint2* __restrict__ g, const float* __restrict__ bias,
    const __half* __restrict__ w2h, __half* __restrict__ out) {
  __shared__ __half hL[16 * 136];
  int wid = threadIdx.x >> 6, lane = threadIdx.x & 63;
  int half_ = lane >> 5, sub = lane & 31;
  // zero-pad rows 8..15 (MFMA reads them; their C rows are discarded)
  for (int i = threadIdx.x; i < 8 * 136; i += 256)
    hL[8 * 136 + i] = __float2half_rn(0.f);
  int lrow = wid * 2 + half_;                // 0..7 within block
  int row = blockIdx.x * 8 + lrow;           // grid exact: row < n
  float4 a = gather_row_half(rowptr, edges, g, row, sub);
  float4 b = ((const float4*)bias)[sub];
  __half2* hp = (__half2*)&hL[lrow * 136 + sub * 4];
  hp[0] = __floats2half2_rn(selu_f(a.x + b.x), selu_f(a.y + b.y));
  hp[1] = __floats2half2_rn(selu_f(a.z + b.z), selu_f(a.w + b.w));
  __syncthreads();
  // C[16x128] = hL @ W2 ; wave w owns col-tiles 2w, 2w+1
  f32x4 acc0 = {0.f, 0.f, 0.f, 0.f}, acc1 = {0.f, 0.f, 0.f, 0.f};
  const f16x8* w8 = (const f16x8*)w2h;
#pragma unroll
  for (int ks = 0; ks < 4; ++ks) {
    f16x8 af = *(const f16x8*)&hL[(lane & 15) * 136 + ks * 32 + (lane >> 4) * 8];
    f16x8 bf0 = w8[((wid * 2 + 0) * 4 + ks) * 64 + lane];
    f16x8 bf1 = w8[((wid * 2 + 1) * 4 + ks) * 64 + lane];
    acc0 = __builtin_amdgcn_mfma_f32_16x16x32_f16(af, bf0, acc0, 0, 0, 0);
    acc1 = __builtin_amdgcn_mfma_f32_16x16x32_f16(af, bf1, acc1, 0, 0, 0);
  }
  // C/D layout: col = lane&15 (+16*tile), row = (lane>>4)*4 + reg; keep rows 0..7
  int hi = lane >> 4;
  if (hi < 2) {
    int crow = blockIdx.x * 8 + hi * 4;
    int c0 = wid * 32 + (lane & 15);
#pragma unroll
    for (int r = 0; r < 4; ++r) {
      out[(size_t)(crow + r) * 128 + c0]      = __float2half_rn(acc0[r]);
      out[(size_t)(crow + r) * 128 + c0 + 16] = __float2half_rn(acc1[r]);
    }
  }
}

// ---------- 6b. layer-2: spmm(fp16 bufB) + bias + selu -> fp32 output ----------
__global__ __launch_bounds__(256) void spmm_ep(
    const int* __restrict__ rowptr, const int2* __restrict__ edges,
    const uint2* __restrict__ xh, const float* __restrict__ bias,
    float* __restrict__ out, int n) {
  int wid = threadIdx.x >> 6, lane = threadIdx.x & 63;
  int half = lane >> 5, sub = lane & 31;
  int row = blockIdx.x * 8 + wid * 2 + half;   // grid exact
  float4 a = gather_row_half(rowptr, edges, xh, row, sub);
  float4 b = ((const float4*)bias)[sub];
  float4 r;
  r.x = selu_f(a.x + b.x);
  r.y = selu_f(a.y + b.y);
  r.z = selu_f(a.z + b.z);
  r.w = selu_f(a.w + b.w);
  ((float4*)out)[(size_t)row * 32 + sub] = r;
}

extern "C" void kernel_launch(void* const* d_in, const int* in_sizes, int n_in,
                              void* d_out, int out_size, void* d_ws, size_t ws_size,
                              hipStream_t stream) {
  const float* x   = (const float*)d_in[0];
  const int*   src = (const int*)d_in[1];
  const int*   dst = (const int*)d_in[2];
  const float* ew  = (const float*)d_in[3];
  const float* W1  = (const float*)d_in[4];
  const float* b1  = (const float*)d_in[5];
  const float* W2  = (const float*)d_in[6];
  const float* b2  = (const float*)d_in[7];
  float* out = (float*)d_out;

  // workspace layout (temporal aliasing: edges over sRec; dRec over bufB)
  char* ws = (char*)d_ws;
  int*   dMat    = (int*)(ws + 0);              //   200,704 B (196*256*4)
  int*   sMat    = (int*)(ws + 200704);         //   200,704 B -> 401,408
  float* inv_out = (float*)(ws + 401408);       //   200,000 B -> 601,408
  int*   rowptr  = (int*)(ws + 601408);         //   200,004 B -> 801,412
  __half* w2h    = (__half*)(ws + 801424);      //    32,768 B -> 834,192 (16B)
  // union region A: sRec (3.2 MB, dead after bucket_src_reduce) / edges (6.4 MB)
  unsigned* sRec = (unsigned*)(ws + 834192);
  int2*  edges   = (int2*)(ws + 834192);        // -> 7,234,192
  __half* bufG   = (__half*)(ws + 7234192);     // 12.8 MB -> 20,034,192
  // union region B: dRec (6.4 MB, dead before spmm_selu_gemm writes bufB)
  int2*  dRec    = (int2*)(ws + 20034192);
  __half* bufB   = (__half*)(ws + 20034192);    // 12.8 MB -> 32,834,192

  // 1. bucket histograms (src & dst) + W2 fragment transform
  pass_hist<<<NBLK_AB + 1, 256, 0, stream>>>(src, dst, dMat, sMat, W2, w2h);
  // 2. exclusive scan of both count matrices
  scan_mat<<<2, 1024, 0, stream>>>(dMat, sMat);
  // 3. exact-slot scatter into bucket regions || bufG = fp16(x @ W1)
  fused_scatter_gemm<<<NBLK_AB + GEMM_BLOCKS, 256, 0, stream>>>(
      src, dst, ew, dMat, sMat, dRec, sRec, x, W1, bufG);
  // 4. src-side reduction -> inv_out
  bucket_src_reduce<<<NB_BUCKET, 256, 0, stream>>>(sRec, sMat, inv_out);
  // 5. dst-side build -> rowptr + final CSR edges (src, c)
  bucket_dst_build<<<NB_BUCKET, 256, 0, stream>>>(dRec, dMat, inv_out,
                                                  rowptr, edges);

  const int RB8 = N_NODES / 8;                 // 6250 (8 rows / block, exact)

  // layer 1 + layer-2 GEMM: bufB = fp16( selu(A_hat·(x@W1) + b1) ) @ W2 (MFMA)
  spmm_selu_gemm<<<RB8, 256, 0, stream>>>(
      rowptr, edges, (const uint2*)bufG, b1, w2h, bufB);
  // layer 2: out = selu(A_hat·bufB + b2)
  spmm_ep<<<RB8, 256, 0, stream>>>(rowptr, edges, (const uint2*)bufB, b2,
                                   out, N_NODES);
}

// Round 8
// 242.760 us; speedup vs baseline: 1.6409x; 1.1001x over previous
//
#include <hip/hip_runtime.h>
#include <hip/hip_fp16.h>
#include <math.h>

#define N_NODES 50000
#define N_EDGES 800000
#define FEAT 128
#define EPS_W 1e-12f

// bucket = node >> 8 : 256 nodes per bucket, 196 buckets covers 50000
#define NB_BUCKET 196
#define NBLK_AB 256          // blocks for hist/scatter passes
#define CHUNK 3125           // edges per pass block (256*3125 = 800000)
#define SCAN_N (NB_BUCKET * NBLK_AB)   // 50176 = 49*1024 exactly
#define GEMM_BLOCKS 3125     // 50000 / 16

typedef unsigned long long u64;
typedef _Float16 f16x8 __attribute__((ext_vector_type(8)));
typedef float f32x4 __attribute__((ext_vector_type(4)));

// ---------- helpers ----------
__device__ __forceinline__ float selu_f(float x) {
  const float scale = 1.0507009873554805f;
  const float alpha = 1.6732632423543772f;
  return x > 0.f ? scale * x : scale * alpha * expm1f(x);
}

__device__ __forceinline__ float2 h2f2(unsigned int u) {
  __half2 h = *reinterpret_cast<__half2*>(&u);
  return __half22float2(h);
}

// ---------- MFMA GEMM body: 16 rows of A(fp32) @ W(frag fp16) -> fp16 out ----
// A rows row0..row0+15 (all valid: 3125*16 = 50000 exact). 4 waves cover 128
// cols (2 col-tiles each). Fragment mapping identical to the r6-verified w2h
// path: af rows = lane&15, k = ks*32 + (lane>>4)*8 + j.
__device__ __forceinline__ void gemm16_mfma_body(
    const float* __restrict__ A, const __half* __restrict__ wh,
    __half* __restrict__ out, int row0, __half* aL /*16*136 LDS*/) {
  int t = threadIdx.x;
  for (int i = t; i < 16 * 32; i += 256) {       // i = float4 index
    int r = i >> 5, c4 = i & 31;
    float4 v = ((const float4*)(A + (size_t)(row0 + r) * 128))[c4];
    __half2* hp = (__half2*)&aL[r * 136 + c4 * 4];
    hp[0] = __floats2half2_rn(v.x, v.y);
    hp[1] = __floats2half2_rn(v.z, v.w);
  }
  __syncthreads();
  int wid = t >> 6, lane = t & 63;
  f32x4 acc0 = {0.f, 0.f, 0.f, 0.f}, acc1 = {0.f, 0.f, 0.f, 0.f};
  const f16x8* w8 = (const f16x8*)wh;
#pragma unroll
  for (int ks = 0; ks < 4; ++ks) {
    f16x8 af = *(const f16x8*)&aL[(lane & 15) * 136 + ks * 32 + (lane >> 4) * 8];
    f16x8 bf0 = w8[((wid * 2 + 0) * 4 + ks) * 64 + lane];
    f16x8 bf1 = w8[((wid * 2 + 1) * 4 + ks) * 64 + lane];
    acc0 = __builtin_amdgcn_mfma_f32_16x16x32_f16(af, bf0, acc0, 0, 0, 0);
    acc1 = __builtin_amdgcn_mfma_f32_16x16x32_f16(af, bf1, acc1, 0, 0, 0);
  }
  // C/D: col = lane&15 (+16*tile), row = (lane>>4)*4 + reg
  int crow = row0 + (lane >> 4) * 4;
  int c0 = wid * 32 + (lane & 15);
#pragma unroll
  for (int r = 0; r < 4; ++r) {
    out[(size_t)(crow + r) * 128 + c0]      = __float2half_rn(acc0[r]);
    out[(size_t)(crow + r) * 128 + c0 + 16] = __float2half_rn(acc1[r]);
  }
}

// ---------- 1. per-block bucket histograms + W1/W2 fragment transforms -------
// Blocks NBLK_AB, NBLK_AB+1: transform W1/W2 (fp32 [k][col]) into
// fragment-major fp16: wh[((nt*4+ks)*64+l)*8 + j] = W[ks*32+(l>>4)*8+j][nt*16+(l&15)]
__global__ __launch_bounds__(256) void pass_hist(
    const int* __restrict__ src, const int* __restrict__ dst,
    int* __restrict__ dMat, int* __restrict__ sMat,
    const float* __restrict__ W1, const float* __restrict__ W2,
    __half* __restrict__ w1h, __half* __restrict__ w2h) {
  if (blockIdx.x >= NBLK_AB) {
    const float* Wsrc = (blockIdx.x == NBLK_AB) ? W1 : W2;
    __half* wdst = (blockIdx.x == NBLK_AB) ? w1h : w2h;
    for (int f = threadIdx.x; f < 2048; f += 256) {
      int l = f & 63, ks = (f >> 6) & 3, nt = f >> 8;
      int kbase = ks * 32 + (l >> 4) * 8;
      int col = nt * 16 + (l & 15);
      __align__(16) __half tmp[8];
#pragma unroll
      for (int j = 0; j < 8; ++j)
        tmp[j] = __float2half_rn(Wsrc[(kbase + j) * 128 + col]);
      *(uint4*)&wdst[f * 8] = *(const uint4*)tmp;
    }
    return;
  }
  __shared__ int hd[NB_BUCKET], hs[NB_BUCKET];
  for (int i = threadIdx.x; i < NB_BUCKET; i += 256) { hd[i] = 0; hs[i] = 0; }
  __syncthreads();
  int blk = blockIdx.x;
  int base = blk * CHUNK;
  for (int i = threadIdx.x; i < CHUNK; i += 256) {
    int e = base + i;
    atomicAdd(&hd[dst[e] >> 8], 1);
    atomicAdd(&hs[src[e] >> 8], 1);
  }
  __syncthreads();
  for (int i = threadIdx.x; i < NB_BUCKET; i += 256) {
    dMat[i * NBLK_AB + blk] = hd[i];
    sMat[i * NBLK_AB + blk] = hs[i];
  }
}

// ---------- 2. in-place exclusive scan of the two 50176-entry matrices --------
__global__ __launch_bounds__(1024) void scan_mat(int* __restrict__ dMat,
                                                 int* __restrict__ sMat) {
  int* m = (blockIdx.x == 0) ? dMat : sMat;
  __shared__ int sh[1024];
  int t = threadIdx.x;
  const int CH = 49;  // 1024*49 = 50176 == SCAN_N exactly
  int s0 = t * CH;
  int v[CH];
  int sum = 0;
#pragma unroll
  for (int j = 0; j < CH; ++j) {
    v[j] = m[s0 + j];
    sum += v[j];
  }
  sh[t] = sum;
  __syncthreads();
  for (int off = 1; off < 1024; off <<= 1) {
    int x = (t >= off) ? sh[t - off] : 0;
    __syncthreads();
    sh[t] += x;
    __syncthreads();
  }
  int excl = sh[t] - sum;
#pragma unroll
  for (int j = 0; j < CH; ++j) {
    m[s0 + j] = excl;
    excl += v[j];
  }
}

// ---------- 3. FUSED: exact-slot bucket scatter (no global atomics) || GEMM ---
// dRec: int2 { (src<<8)|dstLow, ew_bits }   sRec: u32 { srcLow<<24 | Q23(ew) }
__global__ __launch_bounds__(256) void fused_scatter_gemm(
    const int* __restrict__ src, const int* __restrict__ dst,
    const float* __restrict__ ew,
    const int* __restrict__ dMat, const int* __restrict__ sMat,
    int2* __restrict__ dRec, unsigned* __restrict__ sRec,
    const float* __restrict__ x, const __half* __restrict__ w1h,
    __half* __restrict__ bufG) {
  __shared__ __half aL[16 * 136];
  __shared__ int curD[NB_BUCKET], curS[NB_BUCKET];
  if (blockIdx.x >= NBLK_AB) {
    gemm16_mfma_body(x, w1h, bufG, (blockIdx.x - NBLK_AB) * 16, aL);
    return;
  }
  int blk = blockIdx.x;
  for (int i = threadIdx.x; i < NB_BUCKET; i += 256) {
    curD[i] = dMat[i * NBLK_AB + blk];
    curS[i] = sMat[i * NBLK_AB + blk];
  }
  __syncthreads();
  int base = blk * CHUNK;
  for (int i = threadIdx.x; i < CHUNK; i += 256) {
    int e = base + i;
    int s = src[e], d = dst[e];
    float w = ew[e];
    int pd = atomicAdd(&curD[d >> 8], 1);           // LDS atomic
    int2 r; r.x = (s << 8) | (d & 255); r.y = __float_as_int(w);
    dRec[pd] = r;
    int ps = atomicAdd(&curS[s >> 8], 1);           // LDS atomic
    unsigned q = (unsigned)__float2uint_rn(w * 8388608.0f) & 0xFFFFFFu;  // Q23
    sRec[ps] = ((unsigned)(s & 255) << 24) | q;
  }
}

// ---------- 4. per-bucket src reduction -> inv_out ----------
__global__ __launch_bounds__(256) void bucket_src_reduce(
    const unsigned* __restrict__ sRec, const int* __restrict__ sMat,
    float* __restrict__ inv_out) {
  __shared__ float wdeg[256];
  __shared__ int cnt[256];
  int b = blockIdx.x, t = threadIdx.x;
  wdeg[t] = 0.f; cnt[t] = 0;
  __syncthreads();
  int s0 = sMat[b * NBLK_AB];
  int s1 = (b == NB_BUCKET - 1) ? N_EDGES : sMat[(b + 1) * NBLK_AB];
  for (int i = s0 + t; i < s1; i += 256) {
    unsigned r = sRec[i];
    int node = r >> 24;
    float w = (float)(r & 0xFFFFFFu) * (1.0f / 8388608.0f);
    atomicAdd(&wdeg[node], w);
    atomicAdd(&cnt[node], 1);
  }
  __syncthreads();
  int nodeg = b * 256 + t;
  if (nodeg < N_NODES) {
    inv_out[nodeg] = (1.0f / sqrtf(fmaxf(wdeg[t], EPS_W))) *
                     (1.0f / sqrtf(fmaxf((float)cnt[t], 1.0f)));
  }
}

// ---------- 5. per-bucket dst build: rowptr + rank + final CSR edges ----------
__global__ __launch_bounds__(256) void bucket_dst_build(
    const int2* __restrict__ dRec, const int* __restrict__ dMat,
    const float* __restrict__ inv_out,
    int* __restrict__ rowptr, int2* __restrict__ edges) {
  __shared__ float wdeg[256];
  __shared__ int cnt[256];
  __shared__ int excl[256];
  __shared__ float invin[256];
  __shared__ int cur[256];
  int b = blockIdx.x, t = threadIdx.x;
  wdeg[t] = 0.f; cnt[t] = 0;
  __syncthreads();
  int s0 = dMat[b * NBLK_AB];
  int s1 = (b == NB_BUCKET - 1) ? N_EDGES : dMat[(b + 1) * NBLK_AB];
  for (int i = s0 + t; i < s1; i += 256) {
    int2 r = dRec[i];
    int node = r.x & 255;
    atomicAdd(&cnt[node], 1);
    atomicAdd(&wdeg[node], __int_as_float(r.y));
  }
  __syncthreads();
  int myc = cnt[t];
  excl[t] = myc;
  __syncthreads();
  for (int off = 1; off < 256; off <<= 1) {
    int x = (t >= off) ? excl[t - off] : 0;
    __syncthreads();
    excl[t] += x;
    __syncthreads();
  }
  int myexcl = excl[t] - myc;
  int nodeg = b * 256 + t;
  if (nodeg < N_NODES) rowptr[nodeg] = s0 + myexcl;
  if (b == NB_BUCKET - 1 && t == 0) rowptr[N_NODES] = N_EDGES;
  invin[t] = (1.0f / sqrtf(fmaxf(wdeg[t], EPS_W))) *
             (1.0f / sqrtf(fmaxf((float)cnt[t], 1.0f)));
  cur[t] = s0 + myexcl;
  __syncthreads();
  for (int i = s0 + t; i < s1; i += 256) {
    int2 r = dRec[i];
    int node = r.x & 255;
    int srcn = ((unsigned)r.x) >> 8;
    float w = __int_as_float(r.y);
    float c = w * inv_out[srcn] * invin[node];
    int pos = atomicAdd(&cur[node], 1);             // LDS atomic -> rank
    int2 rec; rec.x = srcn; rec.y = __float_as_int(c);
    edges[pos] = rec;
  }
}

// ---------- half-wave gather: 32 lanes cover a 128-wide fp16 row ----------
__device__ __forceinline__ float4 gather_row_half(
    const int* __restrict__ rowptr, const int2* __restrict__ edges,
    const uint2* __restrict__ xh /* row stride 32 */, int row, int sub) {
  int beg = rowptr[row], end = rowptr[row + 1];
  float4 acc = make_float4(0.f, 0.f, 0.f, 0.f);
  int e = beg;
  for (; e + 7 < end; e += 8) {
    int2 p0 = edges[e + 0], p1 = edges[e + 1], p2 = edges[e + 2], p3 = edges[e + 3];
    int2 p4 = edges[e + 4], p5 = edges[e + 5], p6 = edges[e + 6], p7 = edges[e + 7];
    uint2 q0 = xh[(size_t)p0.x * 32 + sub];
    uint2 q1 = xh[(size_t)p1.x * 32 + sub];
    uint2 q2 = xh[(size_t)p2.x * 32 + sub];
    uint2 q3 = xh[(size_t)p3.x * 32 + sub];
    uint2 q4 = xh[(size_t)p4.x * 32 + sub];
    uint2 q5 = xh[(size_t)p5.x * 32 + sub];
    uint2 q6 = xh[(size_t)p6.x * 32 + sub];
    uint2 q7 = xh[(size_t)p7.x * 32 + sub];
#define ACC_EDGE(P, Q)                                              \
    {                                                               \
      float cc = __int_as_float(P.y);                               \
      float2 lo = h2f2(Q.x);                                        \
      float2 hi = h2f2(Q.y);                                        \
      acc.x += cc * lo.x; acc.y += cc * lo.y;                       \
      acc.z += cc * hi.x; acc.w += cc * hi.y;                       \
    }
    ACC_EDGE(p0, q0) ACC_EDGE(p1, q1) ACC_EDGE(p2, q2) ACC_EDGE(p3, q3)
    ACC_EDGE(p4, q4) ACC_EDGE(p5, q5) ACC_EDGE(p6, q6) ACC_EDGE(p7, q7)
  }
  for (; e < end; ++e) {
    int2 p0 = edges[e];
    uint2 q0 = xh[(size_t)p0.x * 32 + sub];
    ACC_EDGE(p0, q0)
  }
#undef ACC_EDGE
  return acc;
}

// ---------- 6a. layer-1: spmm + bias + selu + MFMA @W2 -> fp16 bufB ----------
// 8 rows/block (gather TLP preserved). MFMA M-dim zero-padded to 16.
__global__ __launch_bounds__(256) void spmm_selu_gemm(
    const int* __restrict__ rowptr, const int2* __restrict__ edges,
    const uint2* __restrict__ g, const float* __restrict__ bias,
    const __half* __restrict__ w2h, __half* __restrict__ out) {
  __shared__ __half hL[16 * 136];
  int wid = threadIdx.x >> 6, lane = threadIdx.x & 63;
  int half_ = lane >> 5, sub = lane & 31;
  // zero-pad rows 8..15 (MFMA reads them; their C rows are discarded)
  for (int i = threadIdx.x; i < 8 * 136; i += 256)
    hL[8 * 136 + i] = __float2half_rn(0.f);
  int lrow = wid * 2 + half_;                // 0..7 within block
  int row = blockIdx.x * 8 + lrow;           // grid exact: row < n
  float4 a = gather_row_half(rowptr, edges, g, row, sub);
  float4 b = ((const float4*)bias)[sub];
  __half2* hp = (__half2*)&hL[lrow * 136 + sub * 4];
  hp[0] = __floats2half2_rn(selu_f(a.x + b.x), selu_f(a.y + b.y));
  hp[1] = __floats2half2_rn(selu_f(a.z + b.z), selu_f(a.w + b.w));
  __syncthreads();
  // C[16x128] = hL @ W2 ; wave w owns col-tiles 2w, 2w+1
  f32x4 acc0 = {0.f, 0.f, 0.f, 0.f}, acc1 = {0.f, 0.f, 0.f, 0.f};
  const f16x8* w8 = (const f16x8*)w2h;
#pragma unroll
  for (int ks = 0; ks < 4; ++ks) {
    f16x8 af = *(const f16x8*)&hL[(lane & 15) * 136 + ks * 32 + (lane >> 4) * 8];
    f16x8 bf0 = w8[((wid * 2 + 0) * 4 + ks) * 64 + lane];
    f16x8 bf1 = w8[((wid * 2 + 1) * 4 + ks) * 64 + lane];
    acc0 = __builtin_amdgcn_mfma_f32_16x16x32_f16(af, bf0, acc0, 0, 0, 0);
    acc1 = __builtin_amdgcn_mfma_f32_16x16x32_f16(af, bf1, acc1, 0, 0, 0);
  }
  // C/D layout: col = lane&15 (+16*tile), row = (lane>>4)*4 + reg; keep rows 0..7
  int hi = lane >> 4;
  if (hi < 2) {
    int crow = blockIdx.x * 8 + hi * 4;
    int c0 = wid * 32 + (lane & 15);
#pragma unroll
    for (int r = 0; r < 4; ++r) {
      out[(size_t)(crow + r) * 128 + c0]      = __float2half_rn(acc0[r]);
      out[(size_t)(crow + r) * 128 + c0 + 16] = __float2half_rn(acc1[r]);
    }
  }
}

// ---------- 6b. layer-2: spmm(fp16 bufB) + bias + selu -> fp32 output ----------
__global__ __launch_bounds__(256) void spmm_ep(
    const int* __restrict__ rowptr, const int2* __restrict__ edges,
    const uint2* __restrict__ xh, const float* __restrict__ bias,
    float* __restrict__ out, int n) {
  int wid = threadIdx.x >> 6, lane = threadIdx.x & 63;
  int half = lane >> 5, sub = lane & 31;
  int row = blockIdx.x * 8 + wid * 2 + half;   // grid exact
  float4 a = gather_row_half(rowptr, edges, xh, row, sub);
  float4 b = ((const float4*)bias)[sub];
  float4 r;
  r.x = selu_f(a.x + b.x);
  r.y = selu_f(a.y + b.y);
  r.z = selu_f(a.z + b.z);
  r.w = selu_f(a.w + b.w);
  ((float4*)out)[(size_t)row * 32 + sub] = r;
}

extern "C" void kernel_launch(void* const* d_in, const int* in_sizes, int n_in,
                              void* d_out, int out_size, void* d_ws, size_t ws_size,
                              hipStream_t stream) {
  const float* x   = (const float*)d_in[0];
  const int*   src = (const int*)d_in[1];
  const int*   dst = (const int*)d_in[2];
  const float* ew  = (const float*)d_in[3];
  const float* W1  = (const float*)d_in[4];
  const float* b1  = (const float*)d_in[5];
  const float* W2  = (const float*)d_in[6];
  const float* b2  = (const float*)d_in[7];
  float* out = (float*)d_out;

  // workspace layout (temporal aliasing: edges over sRec; dRec over bufB)
  char* ws = (char*)d_ws;
  int*   dMat    = (int*)(ws + 0);              //   200,704 B (196*256*4)
  int*   sMat    = (int*)(ws + 200704);         //   200,704 B -> 401,408
  float* inv_out = (float*)(ws + 401408);       //   200,000 B -> 601,408
  int*   rowptr  = (int*)(ws + 601408);         //   200,004 B -> 801,412
  __half* w1h    = (__half*)(ws + 801424);      //    32,768 B -> 834,192 (16B)
  __half* w2h    = (__half*)(ws + 834192);      //    32,768 B -> 866,960
  // union region A: sRec (3.2 MB, dead after bucket_src_reduce) / edges (6.4 MB)
  unsigned* sRec = (unsigned*)(ws + 866960);
  int2*  edges   = (int2*)(ws + 866960);        // -> 7,266,960
  __half* bufG   = (__half*)(ws + 7266960);     // 12.8 MB -> 20,066,960
  // union region B: dRec (6.4 MB, dead before spmm_selu_gemm writes bufB)
  int2*  dRec    = (int2*)(ws + 20066960);
  __half* bufB   = (__half*)(ws + 20066960);    // 12.8 MB -> 32,866,960

  // 1. bucket histograms (src & dst) + W1/W2 fragment transforms
  pass_hist<<<NBLK_AB + 2, 256, 0, stream>>>(src, dst, dMat, sMat,
                                             W1, W2, w1h, w2h);
  // 2. exclusive scan of both count matrices
  scan_mat<<<2, 1024, 0, stream>>>(dMat, sMat);
  // 3. exact-slot scatter into bucket regions || bufG = fp16(x @ W1) via MFMA
  fused_scatter_gemm<<<NBLK_AB + GEMM_BLOCKS, 256, 0, stream>>>(
      src, dst, ew, dMat, sMat, dRec, sRec, x, w1h, bufG);
  // 4. src-side reduction -> inv_out
  bucket_src_reduce<<<NB_BUCKET, 256, 0, stream>>>(sRec, sMat, inv_out);
  // 5. dst-side build -> rowptr + final CSR edges (src, c)
  bucket_dst_build<<<NB_BUCKET, 256, 0, stream>>>(dRec, dMat, inv_out,
                                                  rowptr, edges);

  const int RB8 = N_NODES / 8;                 // 6250 (8 rows / block, exact)

  // layer 1 + layer-2 GEMM: bufB = fp16( selu(A_hat·(x@W1) + b1) ) @ W2 (MFMA)
  spmm_selu_gemm<<<RB8, 256, 0, stream>>>(
      rowptr, edges, (const uint2*)bufG, b1, w2h, bufB);
  // layer 2: out = selu(A_hat·bufB + b2)
  spmm_ep<<<RB8, 256, 0, stream>>>(rowptr, edges, (const uint2*)bufB, b2,
                                   out, N_NODES);
}